// Round 1
// baseline (1154.620 us; speedup 1.0000x reference)
//
#include <hip/hip_runtime.h>

#define B_ 128
#define I_ 2000
#define K_ 512
#define R_ 64
#define H_ 128

// ---------------- encoder: h = relu(x@W1+b1); mu,logvar,z ----------------
// one block per batch row b; 512 threads = 4-way split over I, 128 j-columns
__global__ __launch_bounds__(512) void encoder_kernel(
    const float* __restrict__ x, const float* __restrict__ W1, const float* __restrict__ b1,
    const float* __restrict__ Wmu, const float* __restrict__ bmu,
    const float* __restrict__ Wlv, const float* __restrict__ blv,
    const float* __restrict__ eps,
    float* __restrict__ mu_out, float* __restrict__ lv_out, float* __restrict__ z_out)
{
    __shared__ float xs[I_];          // 8 KB: x row
    __shared__ float hpart[4][H_];    // split-K partials
    __shared__ float hrow[H_];
    __shared__ float mus[R_];
    __shared__ float lvs[R_];
    const int b = blockIdx.x;
    const int tid = threadIdx.x;

    for (int i = tid; i < I_; i += 512) xs[i] = x[b * I_ + i];
    __syncthreads();

    const int j = tid & (H_ - 1);
    const int part = tid >> 7;        // 0..3, each sums 500 i's
    float acc = 0.f;
    #pragma unroll 4
    for (int i = part * 500; i < part * 500 + 500; ++i)
        acc = fmaf(xs[i], W1[i * H_ + j], acc);   // W1 read coalesced over j
    hpart[part][j] = acc;
    __syncthreads();

    if (tid < H_) {
        float v = hpart[0][tid] + hpart[1][tid] + hpart[2][tid] + hpart[3][tid] + b1[tid];
        hrow[tid] = fmaxf(v, 0.f);
    }
    __syncthreads();

    if (tid < R_) {
        float m = bmu[tid];
        #pragma unroll 8
        for (int jj = 0; jj < H_; ++jj) m = fmaf(hrow[jj], Wmu[jj * R_ + tid], m);
        mus[tid] = m;
        mu_out[b * R_ + tid] = m;
    } else if (tid < 2 * R_) {
        const int r = tid - R_;
        float lv = blv[r];
        #pragma unroll 8
        for (int jj = 0; jj < H_; ++jj) lv = fmaf(hrow[jj], Wlv[jj * R_ + r], lv);
        lvs[r] = lv;
        lv_out[b * R_ + r] = lv;
    }
    __syncthreads();

    if (tid < R_) {
        z_out[b * R_ + tid] = mus[tid] + eps[b * R_ + tid] * expf(0.5f * lvs[tid]);
    }
}

// ---------------- decoder: X_hat[b,i,k] = sum_r z[b,r]*A[i,r]*C[k,r] ------
// grid = B * 32 i-tiles * 8 k-tiles; block = 256 threads; 64x64 tile, 4x4/thread.
// LDS layout: sA[row][ r XOR-swizzled by (row>>2)&7 ] so compute-side float4
// reads hit distinct bank quads (conflict-free); same for sC.
__global__ __launch_bounds__(256) void decode_kernel(
    const float* __restrict__ A, const float* __restrict__ C,
    const float* __restrict__ z, float* __restrict__ Xhat)
{
    __shared__ __align__(16) float sA[64][64];   // 16 KB, zA tile (z premultiplied)
    __shared__ __align__(16) float sC[64][64];   // 16 KB
    __shared__ __align__(16) float zs[R_];

    const int tid = threadIdx.x;
    const int bid = blockIdx.x;
    const int kt = bid & 7;           // 8 k-tiles (innermost: C walks L2)
    const int it = (bid >> 3) & 31;   // 32 i-tiles
    const int b  = bid >> 8;          // batch
    const int i0 = it * 64, k0 = kt * 64;

    if (tid < R_) zs[tid] = z[b * R_ + tid];
    __syncthreads();

    // stage zA-tile and C-tile, float4 global loads (coalesced), swizzled LDS writes
    #pragma unroll
    for (int s = 0; s < 4; ++s) {
        const int idx = tid + s * 256;       // 0..1023 float4 slots
        const int row = idx >> 4;            // 0..63
        const int q   = idx & 15;            // r-group (4 floats)
        const int swq = q ^ ((row >> 2) & 7);

        const int gi = i0 + row;
        float4 av;
        if (gi < I_) {
            av = *(const float4*)&A[gi * R_ + q * 4];
            const float4 zv = *(const float4*)&zs[q * 4];
            av.x *= zv.x; av.y *= zv.y; av.z *= zv.z; av.w *= zv.w;
        } else {
            av = make_float4(0.f, 0.f, 0.f, 0.f);
        }
        *(float4*)&sA[row][swq * 4] = av;

        const float4 cv = *(const float4*)&C[(k0 + row) * R_ + q * 4];
        *(float4*)&sC[row][swq * 4] = cv;
    }
    __syncthreads();

    const int tx = tid & 15;          // k direction
    const int ty = tid >> 4;          // i direction
    const int sa_sw = (ty & 7) << 2;  // (row>>2)&7 == ty for rows 4*ty+ii
    const int sc_sw = (tx & 7) << 2;

    float acc[4][4] = {};
    #pragma unroll
    for (int g = 0; g < 16; ++g) {    // 16 r-groups of 4
        float4 a[4], c[4];
        #pragma unroll
        for (int ii = 0; ii < 4; ++ii)
            a[ii] = *(const float4*)&sA[ty * 4 + ii][(g * 4) ^ sa_sw];
        #pragma unroll
        for (int kk = 0; kk < 4; ++kk)
            c[kk] = *(const float4*)&sC[tx * 4 + kk][(g * 4) ^ sc_sw];
        #pragma unroll
        for (int ii = 0; ii < 4; ++ii) {
            #pragma unroll
            for (int kk = 0; kk < 4; ++kk) {
                acc[ii][kk] = fmaf(a[ii].x, c[kk].x, acc[ii][kk]);
                acc[ii][kk] = fmaf(a[ii].y, c[kk].y, acc[ii][kk]);
                acc[ii][kk] = fmaf(a[ii].z, c[kk].z, acc[ii][kk]);
                acc[ii][kk] = fmaf(a[ii].w, c[kk].w, acc[ii][kk]);
            }
        }
    }

    const size_t base = (size_t)b * ((size_t)I_ * K_);
    #pragma unroll
    for (int ii = 0; ii < 4; ++ii) {
        const int gi = i0 + ty * 4 + ii;
        if (gi < I_) {
            const float4 v = make_float4(acc[ii][0], acc[ii][1], acc[ii][2], acc[ii][3]);
            *(float4*)&Xhat[base + (size_t)gi * K_ + k0 + tx * 4] = v;
        }
    }
}

extern "C" void kernel_launch(void* const* d_in, const int* in_sizes, int n_in,
                              void* d_out, int out_size, void* d_ws, size_t ws_size,
                              hipStream_t stream) {
    const float* x   = (const float*)d_in[0];
    const float* W1  = (const float*)d_in[1];
    const float* b1  = (const float*)d_in[2];
    const float* Wmu = (const float*)d_in[3];
    const float* bmu = (const float*)d_in[4];
    const float* Wlv = (const float*)d_in[5];
    const float* blv = (const float*)d_in[6];
    const float* A   = (const float*)d_in[7];
    const float* C   = (const float*)d_in[8];
    const float* eps = (const float*)d_in[9];

    float* Xhat   = (float*)d_out;
    float* mu_out = Xhat + (size_t)B_ * I_ * K_;
    float* lv_out = mu_out + (size_t)B_ * R_;
    float* z_ws   = (float*)d_ws;   // 32 KB scratch for z

    encoder_kernel<<<B_, 512, 0, stream>>>(x, W1, b1, Wmu, bmu, Wlv, blv, eps,
                                           mu_out, lv_out, z_ws);
    decode_kernel<<<B_ * 32 * 8, 256, 0, stream>>>(A, C, z_ws, Xhat);
}

// Round 5
// 773.869 us; speedup vs baseline: 1.4920x; 1.4920x over previous
//
#include <hip/hip_runtime.h>

#define B_ 128
#define I_ 2000
#define K_ 512
#define R_ 64
#define H_ 128

typedef __attribute__((ext_vector_type(8))) __bf16 bf16x8;
typedef __attribute__((ext_vector_type(4))) float f32x4;

// ---------------- encoder: h = relu(x@W1+b1); mu,logvar,z ----------------
__global__ __launch_bounds__(512) void encoder_kernel(
    const float* __restrict__ x, const float* __restrict__ W1, const float* __restrict__ b1,
    const float* __restrict__ Wmu, const float* __restrict__ bmu,
    const float* __restrict__ Wlv, const float* __restrict__ blv,
    const float* __restrict__ eps,
    float* __restrict__ mu_out, float* __restrict__ lv_out, float* __restrict__ z_out)
{
    __shared__ float xs[I_];
    __shared__ float hpart[4][H_];
    __shared__ float hrow[H_];
    __shared__ float mus[R_];
    __shared__ float lvs[R_];
    const int b = blockIdx.x;
    const int tid = threadIdx.x;

    for (int i = tid; i < I_; i += 512) xs[i] = x[b * I_ + i];
    __syncthreads();

    const int j = tid & (H_ - 1);
    const int part = tid >> 7;
    float acc = 0.f;
    #pragma unroll 4
    for (int i = part * 500; i < part * 500 + 500; ++i)
        acc = fmaf(xs[i], W1[i * H_ + j], acc);
    hpart[part][j] = acc;
    __syncthreads();

    if (tid < H_) {
        float v = hpart[0][tid] + hpart[1][tid] + hpart[2][tid] + hpart[3][tid] + b1[tid];
        hrow[tid] = fmaxf(v, 0.f);
    }
    __syncthreads();

    if (tid < R_) {
        float m = bmu[tid];
        #pragma unroll 8
        for (int jj = 0; jj < H_; ++jj) m = fmaf(hrow[jj], Wmu[jj * R_ + tid], m);
        mus[tid] = m;
        mu_out[b * R_ + tid] = m;
    } else if (tid < 2 * R_) {
        const int r = tid - R_;
        float lv = blv[r];
        #pragma unroll 8
        for (int jj = 0; jj < H_; ++jj) lv = fmaf(hrow[jj], Wlv[jj * R_ + r], lv);
        lvs[r] = lv;
        lv_out[b * R_ + r] = lv;
    }
    __syncthreads();

    if (tid < R_) {
        z_out[b * R_ + tid] = mus[tid] + eps[b * R_ + tid] * expf(0.5f * lvs[tid]);
    }
}

// ---------------- pre-split C into bf16 hi/lo --------------------------------
__global__ __launch_bounds__(256) void csplit_kernel(
    const float* __restrict__ C, __bf16* __restrict__ Chi, __bf16* __restrict__ Clo)
{
    const int idx = blockIdx.x * 256 + threadIdx.x;   // 0 .. K_*R_-1 = 32767
    const float v = C[idx];
    const __bf16 h = (__bf16)v;
    Chi[idx] = h;
    Clo[idx] = (__bf16)(v - (float)h);
}

// ---------------- decoder via MFMA ------------------------------------------
// X_hat[b] = (z_b * A) @ C^T.  Block: 64 i-rows x 128 k-cols, 4 waves.
// Wave wi owns rows i0+wi*16 .. +15, all 128 cols (8 col-fragments).
// K=64 split into 2 MFMA k-blocks of 32.  bf16 hi/lo split -> ~fp32 accuracy:
//   acc += a_lo*b_hi + a_hi*b_lo + a_hi*b_hi   (a_lo*b_lo ~ 2^-18, dropped)
// A/B fragments use the SAME lane->k mapping on both operands, so the result
// is invariant to the hardware's internal k permutation. C/D layout per m89:
// col = lane&15, row = (lane>>4)*4 + reg.
__global__ __launch_bounds__(256) void decode_mfma(
    const float* __restrict__ A,
    const __bf16* __restrict__ Chi, const __bf16* __restrict__ Clo,
    const float* __restrict__ z, float* __restrict__ Xhat)
{
    __shared__ __align__(16) float zs[R_];
    const int tid = threadIdx.x;
    const int bid = blockIdx.x;
    const int kt = bid & 3;            // 4 k-tiles of 128
    const int it = (bid >> 2) & 31;    // 32 i-tiles of 64
    const int b  = bid >> 7;           // batch
    const int i0 = it * 64, k0 = kt * 128;

    if (tid < R_) zs[tid] = z[b * R_ + tid];
    __syncthreads();

    const int lane = tid & 63;
    const int wi   = tid >> 6;                 // wave id: i sub-tile
    const int row  = i0 + wi * 16 + (lane & 15);
    const int rg   = (lane >> 4) * 8;          // r-group base within k-block

    f32x4 acc[8];
    #pragma unroll
    for (int f = 0; f < 8; ++f) acc[f] = (f32x4){0.f, 0.f, 0.f, 0.f};

    #pragma unroll
    for (int kb = 0; kb < 2; ++kb) {
        const int r0 = kb * 32 + rg;

        bf16x8 ahi, alo;
        if (row < I_) {
            const f32x4 a0 = *(const f32x4*)&A[row * R_ + r0];
            const f32x4 a1 = *(const f32x4*)&A[row * R_ + r0 + 4];
            const f32x4 z0 = *(const f32x4*)&zs[r0];
            const f32x4 z1 = *(const f32x4*)&zs[r0 + 4];
            #pragma unroll
            for (int j = 0; j < 4; ++j) {
                const float v = a0[j] * z0[j];
                const __bf16 h = (__bf16)v;
                ahi[j] = h; alo[j] = (__bf16)(v - (float)h);
            }
            #pragma unroll
            for (int j = 0; j < 4; ++j) {
                const float v = a1[j] * z1[j];
                const __bf16 h = (__bf16)v;
                ahi[4 + j] = h; alo[4 + j] = (__bf16)(v - (float)h);
            }
        } else {
            #pragma unroll
            for (int j = 0; j < 8; ++j) { ahi[j] = (__bf16)0.f; alo[j] = (__bf16)0.f; }
        }

        #pragma unroll
        for (int f = 0; f < 8; ++f) {
            const int col = k0 + f * 16 + (lane & 15);
            const bf16x8 bhi = *(const bf16x8*)&Chi[col * R_ + r0];
            const bf16x8 blo = *(const bf16x8*)&Clo[col * R_ + r0];
            acc[f] = __builtin_amdgcn_mfma_f32_16x16x32_bf16(alo, bhi, acc[f], 0, 0, 0);
            acc[f] = __builtin_amdgcn_mfma_f32_16x16x32_bf16(ahi, blo, acc[f], 0, 0, 0);
            acc[f] = __builtin_amdgcn_mfma_f32_16x16x32_bf16(ahi, bhi, acc[f], 0, 0, 0);
        }
    }

    const size_t base = (size_t)b * ((size_t)I_ * K_);
    #pragma unroll
    for (int reg = 0; reg < 4; ++reg) {
        const int irow = i0 + wi * 16 + (lane >> 4) * 4 + reg;
        if (irow < I_) {
            const size_t rb = base + (size_t)irow * K_ + k0 + (lane & 15);
            #pragma unroll
            for (int f = 0; f < 8; ++f)
                Xhat[rb + f * 16] = acc[f][reg];
        }
    }
}

extern "C" void kernel_launch(void* const* d_in, const int* in_sizes, int n_in,
                              void* d_out, int out_size, void* d_ws, size_t ws_size,
                              hipStream_t stream) {
    const float* x   = (const float*)d_in[0];
    const float* W1  = (const float*)d_in[1];
    const float* b1  = (const float*)d_in[2];
    const float* Wmu = (const float*)d_in[3];
    const float* bmu = (const float*)d_in[4];
    const float* Wlv = (const float*)d_in[5];
    const float* blv = (const float*)d_in[6];
    const float* A   = (const float*)d_in[7];
    const float* C   = (const float*)d_in[8];
    const float* eps = (const float*)d_in[9];

    float* Xhat   = (float*)d_out;
    float* mu_out = Xhat + (size_t)B_ * I_ * K_;
    float* lv_out = mu_out + (size_t)B_ * R_;

    // workspace layout: z [B*R f32 = 32KB] | Chi [K*R bf16 = 64KB] | Clo [64KB]
    char* ws = (char*)d_ws;
    float*  z_ws = (float*)ws;
    __bf16* Chi  = (__bf16*)(ws + 32 * 1024);
    __bf16* Clo  = (__bf16*)(ws + 96 * 1024);

    encoder_kernel<<<B_, 512, 0, stream>>>(x, W1, b1, Wmu, bmu, Wlv, blv, eps,
                                           mu_out, lv_out, z_ws);
    csplit_kernel<<<(K_ * R_) / 256, 256, 0, stream>>>(C, Chi, Clo);
    decode_mfma<<<B_ * 32 * 4, 256, 0, stream>>>(A, Chi, Clo, z_ws, Xhat);
}

// Round 6
// 599.841 us; speedup vs baseline: 1.9249x; 1.2901x over previous
//
#include <hip/hip_runtime.h>

#define B_ 128
#define I_ 2000
#define K_ 512
#define R_ 64
#define H_ 128
#define BG 4   // batches per decode block

typedef __attribute__((ext_vector_type(8))) __bf16 bf16x8;
typedef __attribute__((ext_vector_type(4))) float f32x4;

// ---------------- encoder: h = relu(x@W1+b1); mu,logvar,z ----------------
__global__ __launch_bounds__(512) void encoder_kernel(
    const float* __restrict__ x, const float* __restrict__ W1, const float* __restrict__ b1,
    const float* __restrict__ Wmu, const float* __restrict__ bmu,
    const float* __restrict__ Wlv, const float* __restrict__ blv,
    const float* __restrict__ eps,
    float* __restrict__ mu_out, float* __restrict__ lv_out, float* __restrict__ z_out)
{
    __shared__ float xs[I_];
    __shared__ float hpart[4][H_];
    __shared__ float hrow[H_];
    __shared__ float mus[R_];
    __shared__ float lvs[R_];
    const int b = blockIdx.x;
    const int tid = threadIdx.x;

    for (int i = tid; i < I_; i += 512) xs[i] = x[b * I_ + i];
    __syncthreads();

    const int j = tid & (H_ - 1);
    const int part = tid >> 7;
    float acc = 0.f;
    #pragma unroll 4
    for (int i = part * 500; i < part * 500 + 500; ++i)
        acc = fmaf(xs[i], W1[i * H_ + j], acc);
    hpart[part][j] = acc;
    __syncthreads();

    if (tid < H_) {
        float v = hpart[0][tid] + hpart[1][tid] + hpart[2][tid] + hpart[3][tid] + b1[tid];
        hrow[tid] = fmaxf(v, 0.f);
    }
    __syncthreads();

    if (tid < R_) {
        float m = bmu[tid];
        #pragma unroll 8
        for (int jj = 0; jj < H_; ++jj) m = fmaf(hrow[jj], Wmu[jj * R_ + tid], m);
        mus[tid] = m;
        mu_out[b * R_ + tid] = m;
    } else if (tid < 2 * R_) {
        const int r = tid - R_;
        float lv = blv[r];
        #pragma unroll 8
        for (int jj = 0; jj < H_; ++jj) lv = fmaf(hrow[jj], Wlv[jj * R_ + r], lv);
        lvs[r] = lv;
        lv_out[b * R_ + r] = lv;
    }
    __syncthreads();

    if (tid < R_) {
        z_out[b * R_ + tid] = mus[tid] + eps[b * R_ + tid] * expf(0.5f * lvs[tid]);
    }
}

// ---------------- pre-split C into bf16 hi/lo --------------------------------
__global__ __launch_bounds__(256) void csplit_kernel(
    const float* __restrict__ C, __bf16* __restrict__ Chi, __bf16* __restrict__ Clo)
{
    const int idx = blockIdx.x * 256 + threadIdx.x;   // 0 .. K_*R_-1
    const float v = C[idx];
    const __bf16 h = (__bf16)v;
    Chi[idx] = h;
    Clo[idx] = (__bf16)(v - (float)h);
}

// ---------------- decoder via MFMA, batch-reuse ------------------------------
// Block = 4 waves, serves BG=4 batches on a 64i x 128k tile.
// C tile (hi+lo) staged to LDS once, reused 4x; A raw loaded once per wave,
// z-split redone per batch (cheap VALU). Stores interleave across the b-loop.
// LDS swizzle: slot(col,g) = col*8 + (g ^ (col&7)); compute-side read has
// lanes c=0..15 hitting quad g^(c&7) -> every bank-quad 2x = free.
__global__ __launch_bounds__(256) void decode_mfma(
    const float* __restrict__ A,
    const __bf16* __restrict__ Chi, const __bf16* __restrict__ Clo,
    const float* __restrict__ z, float* __restrict__ Xhat)
{
    __shared__ __align__(16) __bf16 sChi[128 * 64];   // 16 KB, [col][r] swizzled
    __shared__ __align__(16) __bf16 sClo[128 * 64];   // 16 KB
    __shared__ __align__(16) float zs[BG][R_];        // 1 KB

    const int tid = threadIdx.x;
    const int bid = blockIdx.x;
    const int kt = bid & 3;            // 4 k-tiles of 128
    const int it = (bid >> 2) & 31;    // 32 i-tiles of 64
    const int bg = bid >> 7;           // 32 batch-groups of 4
    const int i0 = it * 64, k0 = kt * 128, b0 = bg * BG;

    // stage z for 4 batches (256 threads = 4*64 exactly)
    zs[tid >> 6][tid & 63] = z[(b0 + (tid >> 6)) * R_ + (tid & 63)];

    // stage C hi/lo tile: 1024 slots of 16B each; global reads fully coalesced
    #pragma unroll
    for (int s = 0; s < 4; ++s) {
        const int idx = tid + s * 256;         // [0,1024)
        const int col = idx >> 3;              // [0,128)
        const int g   = idx & 7;               // r-group of 8
        const int slot = col * 8 + (g ^ (col & 7));
        const size_t gaddr = (size_t)(k0 + col) * R_ + g * 8;
        *(bf16x8*)&sChi[slot * 8] = *(const bf16x8*)&Chi[gaddr];
        *(bf16x8*)&sClo[slot * 8] = *(const bf16x8*)&Clo[gaddr];
    }

    // A raw fragments, loaded once (reused for all 4 batches)
    const int lane = tid & 63;
    const int wi   = tid >> 6;
    const int row  = i0 + wi * 16 + (lane & 15);
    const int rg   = (lane >> 4) * 8;
    f32x4 araw[2][2];
    #pragma unroll
    for (int kb = 0; kb < 2; ++kb) {
        const int r0 = kb * 32 + rg;
        if (row < I_) {
            araw[kb][0] = *(const f32x4*)&A[row * R_ + r0];
            araw[kb][1] = *(const f32x4*)&A[row * R_ + r0 + 4];
        } else {
            araw[kb][0] = (f32x4){0.f, 0.f, 0.f, 0.f};
            araw[kb][1] = (f32x4){0.f, 0.f, 0.f, 0.f};
        }
    }
    __syncthreads();

    const size_t ik = (size_t)I_ * K_;
    #pragma unroll 1
    for (int b = 0; b < BG; ++b) {
        f32x4 acc[8];
        #pragma unroll
        for (int f = 0; f < 8; ++f) acc[f] = (f32x4){0.f, 0.f, 0.f, 0.f};

        #pragma unroll
        for (int kb = 0; kb < 2; ++kb) {
            const int r0 = kb * 32 + rg;
            const f32x4 z0 = *(const f32x4*)&zs[b][r0];
            const f32x4 z1 = *(const f32x4*)&zs[b][r0 + 4];

            bf16x8 ahi, alo;
            #pragma unroll
            for (int j = 0; j < 4; ++j) {
                const float v = araw[kb][0][j] * z0[j];
                const __bf16 h = (__bf16)v;
                ahi[j] = h; alo[j] = (__bf16)(v - (float)h);
            }
            #pragma unroll
            for (int j = 0; j < 4; ++j) {
                const float v = araw[kb][1][j] * z1[j];
                const __bf16 h = (__bf16)v;
                ahi[4 + j] = h; alo[4 + j] = (__bf16)(v - (float)h);
            }

            const int g = kb * 4 + (lane >> 4);
            #pragma unroll
            for (int f = 0; f < 8; ++f) {
                const int col = f * 16 + (lane & 15);
                const int slot = col * 8 + (g ^ (col & 7));
                const bf16x8 bhi = *(const bf16x8*)&sChi[slot * 8];
                const bf16x8 blo = *(const bf16x8*)&sClo[slot * 8];
                acc[f] = __builtin_amdgcn_mfma_f32_16x16x32_bf16(alo, bhi, acc[f], 0, 0, 0);
                acc[f] = __builtin_amdgcn_mfma_f32_16x16x32_bf16(ahi, blo, acc[f], 0, 0, 0);
                acc[f] = __builtin_amdgcn_mfma_f32_16x16x32_bf16(ahi, bhi, acc[f], 0, 0, 0);
            }
        }

        // epilogue for this batch: stores stream while next b computes
        const size_t base = (size_t)(b0 + b) * ik;
        #pragma unroll
        for (int reg = 0; reg < 4; ++reg) {
            const int irow = i0 + wi * 16 + (lane >> 4) * 4 + reg;
            if (irow < I_) {
                const size_t rb = base + (size_t)irow * K_ + k0 + (lane & 15);
                #pragma unroll
                for (int f = 0; f < 8; ++f)
                    Xhat[rb + f * 16] = acc[f][reg];
            }
        }
    }
}

extern "C" void kernel_launch(void* const* d_in, const int* in_sizes, int n_in,
                              void* d_out, int out_size, void* d_ws, size_t ws_size,
                              hipStream_t stream) {
    const float* x   = (const float*)d_in[0];
    const float* W1  = (const float*)d_in[1];
    const float* b1  = (const float*)d_in[2];
    const float* Wmu = (const float*)d_in[3];
    const float* bmu = (const float*)d_in[4];
    const float* Wlv = (const float*)d_in[5];
    const float* blv = (const float*)d_in[6];
    const float* A   = (const float*)d_in[7];
    const float* C   = (const float*)d_in[8];
    const float* eps = (const float*)d_in[9];

    float* Xhat   = (float*)d_out;
    float* mu_out = Xhat + (size_t)B_ * I_ * K_;
    float* lv_out = mu_out + (size_t)B_ * R_;

    // workspace layout: z [B*R f32 = 32KB] | Chi [K*R bf16 = 64KB] | Clo [64KB]
    char* ws = (char*)d_ws;
    float*  z_ws = (float*)ws;
    __bf16* Chi  = (__bf16*)(ws + 32 * 1024);
    __bf16* Clo  = (__bf16*)(ws + 96 * 1024);

    encoder_kernel<<<B_, 512, 0, stream>>>(x, W1, b1, Wmu, bmu, Wlv, blv, eps,
                                           mu_out, lv_out, z_ws);
    csplit_kernel<<<(K_ * R_) / 256, 256, 0, stream>>>(C, Chi, Clo);
    decode_mfma<<<(B_ / BG) * 32 * 4, 256, 0, stream>>>(A, Chi, Clo, z_ws, Xhat);
}